// Round 1
// baseline (1654.318 us; speedup 1.0000x reference)
//
#include <hip/hip_runtime.h>
#include <math.h>

// ---------------------------------------------------------------------------
// LSV Monte Carlo: 16384 paths x 96 steps, per-step NN local vol + hedges.
// Kernel 1: 256 blocks x 1024 threads. Each block owns 64 paths (lane=path),
//           16 waves split the 100-wide MLP columns / hedge strikes.
// Kernel 2: reduce per-block partial sums -> mean / var(ddof=1) -> d_out.
// All fp32 (no MFMA this round) -> VALU-bound, target ~300 us.
// ---------------------------------------------------------------------------

#define MC      16384
#define NSTEP   96
#define NPATH   64                 // paths per block (= lanes per wave)
#define NWAVE   16                 // waves per block
#define BLOCK   (NWAVE * 64)       // 1024 threads
#define NGROUP  (MC / NPATH)       // 256 blocks
#define NPAIR   84                 // 4 maturities * 21 strikes

__device__ __forceinline__ float softplus_f(float x) {
    // stable: max(x,0) + log1p(exp(-|x|))
    return fmaxf(x, 0.f) + log1pf(expf(-fabsf(x)));
}

__global__ __launch_bounds__(BLOCK)
void lsv_sim(const float* __restrict__ S0p,   const float* __restrict__ ratep,
             const float* __restrict__ z,     const float* __restrict__ zzg,
             const float* __restrict__ strikes,
             const float* __restrict__ v0p,   const float* __restrict__ rhop,
             const float* __restrict__ svW1,  const float* __restrict__ svb1,
             const float* __restrict__ svW2,  const float* __restrict__ svb2,
             const float* __restrict__ svW3,  const float* __restrict__ svb3,
             const float* __restrict__ vhW1,  const float* __restrict__ vhb1,
             const float* __restrict__ vhW2,  const float* __restrict__ vhb2,
             const float* __restrict__ vdW1,  const float* __restrict__ vdb1,
             const float* __restrict__ vdW2,  const float* __restrict__ vdb2,
             const float* __restrict__ vvW1,  const float* __restrict__ vvb1,
             const float* __restrict__ vvW2,  const float* __restrict__ vvb2,
             const int*   __restrict__ mats,
             float* __restrict__ psum, float* __restrict__ psq)
{
    const int lane  = threadIdx.x & 63;                                  // path in group
    const int w     = __builtin_amdgcn_readfirstlane((int)(threadIdx.x >> 6)); // wave id (uniform)
    const int gpath = blockIdx.x * NPATH + lane;

    // LDS: h1 transposed [path][k] so layer-2 reads are ds_read_b128,
    //      plus the 16-way partial-output reduction buffer.
    __shared__ float h1s[NPATH * 100];   // 25.6 KB
    __shared__ float red[NWAVE * 64];    //  4.0 KB

    // ---- uniform setup -----------------------------------------------------
    const float rate  = ratep[0];
    const float S0    = S0p[0];
    const float rho_t = tanhf(rhop[0]);
    const float srho  = sqrtf(1.f - rho_t * rho_t);
    const float b3    = svb3[0];
    const float vdb2s = vdb2[0];
    const float vvb2s = vvb2[0];
    int matr[4];
    #pragma unroll
    for (int k = 0; k < 4; k++) matr[k] = mats[k];

    // layer-2 j-slice for this wave: waves 0..3 get 7 cols, 4..15 get 6 (total 100)
    const int jw0  = (w < 4) ? (7 * w) : (6 * w + 4);
    const int jcnt = (w < 4) ? 7 : 6;

    // hedge slice: wave w -> maturity m = w>>2, strikes ss0..ss0+scnt-1 (6+5+5+5=21)
    const int m    = w >> 2;
    const int q4   = w & 3;
    const int ss0  = (q4 == 0) ? 0 : (6 + 5 * (q4 - 1));
    const int scnt = (q4 == 0) ? 6 : 5;

    float Karr[6];
    #pragma unroll
    for (int si = 0; si < 6; si++)
        Karr[si] = strikes[ss0 + ((si < scnt) ? si : 0)];

    // ---- per-path state (identical across the 16 waves; lane = path) ------
    float Slog = logf(S0);
    float S    = expf(Slog);                       // matches ref exp(log S0)
    float V    = (1.f / (1.f + expf(-v0p[0]))) * 0.5f;
    float cv[6];
    #pragma unroll
    for (int si = 0; si < 6; si++) cv[si] = 0.f;

    const float4* hp = reinterpret_cast<const float4*>(h1s + lane * 100); // 400B stride, 16B aligned

    for (int i = 0; i < NSTEP; i++) {
        // ---- uniform per-step scalars (match ref's f32 arithmetic) --------
        const float t0    = (float)i       / 365.0f;
        const float t1    = (float)(i + 1) / 365.0f;
        const float h     = t1 - t0;
        const float sqh   = sqrtf(h);
        const float disc0 = expf(-rate * t0);
        const float disc1 = expf(-rate * t1);
        const int   day   = i + 1;
        int idx = 0;
        while (idx < 3 && day > matr[idx]) idx++;
        const bool im = (day == matr[idx]);

        // ---- P1: s_vol layer 1 -> LDS (k interleaved across waves) -------
        for (int k = w; k < 100; k += NWAVE) {
            float hv = fmaxf(svW1[k] * t0 + svW1[100 + k] * Slog + svW1[200 + k] * V + svb1[k], 0.f);
            h1s[lane * 100 + k] = hv;
        }
        __syncthreads();

        // ---- P2: layer 2 (j-slice) + layer 3 partial ----------------------
        float acc[7];
        #pragma unroll
        for (int jj = 0; jj < 7; jj++) acc[jj] = 0.f;
        #pragma unroll 5
        for (int kk = 0; kk < 25; kk++) {
            const float4 hv = hp[kk];
            const int kb = kk * 4;
            #pragma unroll
            for (int jj = 0; jj < 7; jj++) {
                if (jj < jcnt) {
                    const int j = jw0 + jj;
                    acc[jj] += hv.x * svW2[(kb    ) * 100 + j];
                    acc[jj] += hv.y * svW2[(kb + 1) * 100 + j];
                    acc[jj] += hv.z * svW2[(kb + 2) * 100 + j];
                    acc[jj] += hv.w * svW2[(kb + 3) * 100 + j];
                }
            }
        }
        float pout = 0.f;
        #pragma unroll
        for (int jj = 0; jj < 7; jj++) {
            if (jj < jcnt) {
                const int j = jw0 + jj;
                const float h2 = fmaxf(acc[jj] + svb2[j], 0.f);
                pout += h2 * svW3[j];
            }
        }
        red[w * 64 + lane] = pout;

        // ---- P3: vanilla hedge for my (m, strike-slice) (uses Slog_old) ---
        float h1vh[20];
        #pragma unroll
        for (int j = 0; j < 20; j++)
            h1vh[j] = fmaxf(t0 * vhW1[m * 40 + j] + Slog * vhW1[m * 40 + 20 + j] + vhb1[m * 20 + j], 0.f);
        float cvf[6];
        #pragma unroll
        for (int si = 0; si < 6; si++) {
            if (si < scnt) {
                const int s = ss0 + si;
                float a = vhb2[m * 21 + s];
                #pragma unroll
                for (int j = 0; j < 20; j++)
                    a += h1vh[j] * vhW2[m * 420 + j * 21 + s];
                cvf[si] = softplus_f(a);
            } else cvf[si] = 0.f;
        }
        __syncthreads();

        // ---- P4: finish the step (every wave, redundantly; keeps state in regs)
        float sum = 0.f;
        #pragma unroll
        for (int ww = 0; ww < NWAVE; ww++) sum += red[ww * 64 + lane];
        const float pd = softplus_f(sum + b3);

        const float zi  = z  [gpath * NSTEP + i];
        const float zzi = zzg[gpath * NSTEP + i];
        const float dW  = sqh * zi;
        const float dB  = rho_t * dW + srho * sqh * zzi;

        float vd = vdb2s, vv = vvb2s;
        #pragma unroll
        for (int j = 0; j < 20; j++) {
            vd += fmaxf(V * vdW1[j] + vdb1[j], 0.f) * vdW2[j];
            vv += fmaxf(V * vvW1[j] + vvb1[j], 0.f) * vvW2[j];
        }
        vv = softplus_f(vv);
        const float Vn = V + vd * h + vv * dB;

        const float drift   = rate - 0.5f * pd * pd;
        const float diff    = pd * dW;
        const float drift_c = 1.f + fabsf(drift) * sqh;
        const float diff_c  = 1.f + fabsf(pd) * sqh;
        const float Sln     = Slog + drift * h / drift_c + diff / diff_c;
        const float Sn      = expf(Sln);
        const float dS      = disc1 * Sn - disc0 * S;

        // ---- P5: control-variate accumulate + maturity pricing ------------
        if (m >= idx) {
            #pragma unroll
            for (int si = 0; si < 6; si++)
                if (si < scnt) cv[si] += cvf[si] * dS;
        }
        if (im && m == idx) {
            #pragma unroll
            for (int si = 0; si < 6; si++) {
                if (si < scnt) {
                    const float price = disc1 * fmaxf(Sn - Karr[si], 0.f) - cv[si];
                    float sm = price, sq = price * price;
                    for (int o = 32; o; o >>= 1) {
                        sm += __shfl_xor(sm, o);
                        sq += __shfl_xor(sq, o);
                    }
                    if (lane == 0) {
                        const int q = m * 21 + ss0 + si;
                        psum[q * NGROUP + blockIdx.x] = sm;
                        psq [q * NGROUP + blockIdx.x] = sq;
                    }
                }
            }
        }

        Slog = Sln; S = Sn; V = Vn;
    }
}

__global__ void lsv_finalize(const float* __restrict__ psum,
                             const float* __restrict__ psq,
                             float* __restrict__ out)
{
    const int t = blockIdx.x * blockDim.x + threadIdx.x;
    if (t >= NPAIR) return;
    float s = 0.f, q = 0.f;
    for (int b = 0; b < NGROUP; b++) {
        s += psum[t * NGROUP + b];
        q += psq [t * NGROUP + b];
    }
    const float mean = s * (1.0f / (float)MC);
    const float var  = (q - (float)MC * mean * mean) * (1.0f / (float)(MC - 1));
    out[t]         = mean;   // pv_h  (4,21) row-major
    out[NPAIR + t] = var;    // pv_var
}

extern "C" void kernel_launch(void* const* d_in, const int* in_sizes, int n_in,
                              void* d_out, int out_size, void* d_ws, size_t ws_size,
                              hipStream_t stream)
{
    const float* S0    = (const float*)d_in[0];
    const float* rate  = (const float*)d_in[1];
    const float* z     = (const float*)d_in[2];
    const float* zz    = (const float*)d_in[3];
    // d_in[4] = timegrid (recomputed in-kernel)
    const float* strikes = (const float*)d_in[5];
    const float* v0    = (const float*)d_in[6];
    const float* rho   = (const float*)d_in[7];
    const float* svW1  = (const float*)d_in[8];
    const float* svb1  = (const float*)d_in[9];
    const float* svW2  = (const float*)d_in[10];
    const float* svb2  = (const float*)d_in[11];
    const float* svW3  = (const float*)d_in[12];
    const float* svb3  = (const float*)d_in[13];
    const float* vhW1  = (const float*)d_in[14];
    const float* vhb1  = (const float*)d_in[15];
    const float* vhW2  = (const float*)d_in[16];
    const float* vhb2  = (const float*)d_in[17];
    const float* vdW1  = (const float*)d_in[18];
    const float* vdb1  = (const float*)d_in[19];
    const float* vdW2  = (const float*)d_in[20];
    const float* vdb2  = (const float*)d_in[21];
    const float* vvW1  = (const float*)d_in[22];
    const float* vvb1  = (const float*)d_in[23];
    const float* vvW2  = (const float*)d_in[24];
    const float* vvb2  = (const float*)d_in[25];
    const int*   mats  = (const int*)d_in[26];

    float* psum = (float*)d_ws;                 // NPAIR * NGROUP floats
    float* psq  = psum + NPAIR * NGROUP;        // NPAIR * NGROUP floats

    hipLaunchKernelGGL(lsv_sim, dim3(NGROUP), dim3(BLOCK), 0, stream,
                       S0, rate, z, zz, strikes, v0, rho,
                       svW1, svb1, svW2, svb2, svW3, svb3,
                       vhW1, vhb1, vhW2, vhb2,
                       vdW1, vdb1, vdW2, vdb2,
                       vvW1, vvb1, vvW2, vvb2,
                       mats, psum, psq);

    hipLaunchKernelGGL(lsv_finalize, dim3(1), dim3(128), 0, stream,
                       psum, psq, (float*)d_out);
}